// Round 1
// 220.169 us; speedup vs baseline: 1.0383x; 1.0383x over previous
//
#include <hip/hip_runtime.h>
#include <hip/hip_bf16.h>

#define NB_ 16      // batches
#define LA_ 1024
#define LB_ 1024
#define H_  512

typedef __attribute__((ext_vector_type(8))) short short8;   // 8 bf16 = 4 VGPRs
typedef __attribute__((ext_vector_type(4))) float f32x4;    // MFMA C/D

using bf16 = __hip_bfloat16;

__device__ __forceinline__ float bf2f(unsigned short u) {
    union { unsigned int i; float f; } c; c.i = ((unsigned)u) << 16; return c.f;
}
__device__ __forceinline__ unsigned short f2bf(float f) {
    bf16 h = __float2bfloat16(f);
    return *(unsigned short*)&h;
}

__device__ __forceinline__ void load_lds16(const void* g, void* l) {
    __builtin_amdgcn_global_load_lds(
        (const __attribute__((address_space(1))) void*)g,
        (__attribute__((address_space(3))) void*)l, 16, 0, 0);
}

// ---------------------------------------------------------------------------
// MFMA GEMM core, 256x256 tile, BK=64, 8 waves (2Mx4N), double-buffered
// 128 KiB LDS: C(256x256) = A(256xK) . B^T(256xK), bf16, fp32 acc.
//
// Schedule (T3/T4-lite + T5): per K-tile, issue ALL 8 global_load_lds for
// tile t+1 into the idle buffer at phase 0 (safe: that buffer's readers
// retired at the previous __syncthreads), then 4 quadrant phases of
// {ds_read frags ; s_barrier ; setprio(1) ; 16 MFMA ; setprio(0) ; s_barrier},
// and drain vmcnt only at the tile boundary -> load latency hides under
// ~4 phases of MFMA instead of being exposed per tile (the m97-structure
// stall). LDS tiles [256][64] bf16, 16B chunk slot XOR-swizzled by (row&7)
// (bank-conflict-free, measured 0 conflicts at 128^2).
// Per wave: output 128x64 = acc[8][4] f32x4 (128 VGPR). A-frags cached
// across the pn-pair (32 instead of 48 ds_read_b128 per tile per wave).
// ---------------------------------------------------------------------------
__device__ __forceinline__ void gemm_core256(
    const unsigned short* __restrict__ A, const unsigned short* __restrict__ B,
    int lda, int ldb, int K,
    unsigned short* lds, f32x4 acc[8][4])
{
    const int t = threadIdx.x;
    const int w = t >> 6, lane = t & 63;
    const int wr = w >> 2, wc = w & 3;          // wave grid 2 (M) x 4 (N)
    const int lm = lane & 15, q = lane >> 4;

    // fragment LDS byte offsets for kk=0; kk=1 is addr ^ 64 (chunk bit2 flip)
    int aoff[8], boff[4];
#pragma unroll
    for (int f = 0; f < 8; f++) {
        const int ra = wr * 128 + f * 16 + lm;
        aoff[f] = ra * 128 + ((q ^ (ra & 7)) << 4);
    }
#pragma unroll
    for (int f = 0; f < 4; f++) {
        const int rb = wc * 64 + f * 16 + lm;
        boff[f] = rb * 128 + ((q ^ (rb & 7)) << 4);
    }

    // staging: per buffer fill, 4 instrs x 8 waves cover 256 rows; each wave
    // instr writes 8 rows x 128 B linearly; source chunk pre-swizzled so LDS
    // slot c holds global chunk c ^ (row&7). row&7 == lane>>3 here.
    const int rstep = w * 8 + (lane >> 3);
    const int sc = (lane & 7) ^ (lane >> 3);
    const unsigned short* gA = A + (size_t)rstep * lda + sc * 8;
    const unsigned short* gB = B + (size_t)rstep * ldb + sc * 8;
    char* lA = (char*)lds + w * 1024;            // A buffers: bytes [0,65536)
    char* lB = (char*)lds + 65536 + w * 1024;    // B buffers: bytes [65536,131072)
    const int NT = K >> 6;

    // prologue: stage tile 0 into buffer 0 (full drain once per block)
#pragma unroll
    for (int s = 0; s < 4; s++) {
        load_lds16(gA + (size_t)s * 64 * lda, lA + s * 8192);
        load_lds16(gB + (size_t)s * 64 * ldb, lB + s * 8192);
    }
    __syncthreads();

    int db = 0;
    for (int kt = 0; kt < NT; ++kt) {
        const char* bA = (const char*)lds + db * 32768;
        const char* bB = (const char*)lds + 65536 + db * 32768;
        const int nxt = (db ^ 1) * 32768;
        short8 av[4][2];
#pragma unroll
        for (int p = 0; p < 4; ++p) {
            const int pm = p >> 1, pn = p & 1;
            if (p == 0 && kt + 1 < NT) {
                // issue next tile into idle buffer; drained at tile end only
                const size_t ko = (size_t)(kt + 1) * 64;
#pragma unroll
                for (int s = 0; s < 4; s++) {
                    load_lds16(gA + ko + (size_t)s * 64 * lda, lA + nxt + s * 8192);
                    load_lds16(gB + ko + (size_t)s * 64 * ldb, lB + nxt + s * 8192);
                }
            }
            if (pn == 0) {                       // A-frags reused for pn=0,1
#pragma unroll
                for (int f = 0; f < 4; f++)
#pragma unroll
                    for (int kk = 0; kk < 2; kk++)
                        av[f][kk] = *(const short8*)(bA + (aoff[pm * 4 + f] ^ (kk << 6)));
            }
            short8 bv[2][2];
#pragma unroll
            for (int f = 0; f < 2; f++)
#pragma unroll
                for (int kk = 0; kk < 2; kk++)
                    bv[f][kk] = *(const short8*)(bB + (boff[pn * 2 + f] ^ (kk << 6)));
            __builtin_amdgcn_s_barrier();
            __builtin_amdgcn_s_setprio(1);
#pragma unroll
            for (int kk = 0; kk < 2; kk++)
#pragma unroll
                for (int f = 0; f < 2; f++)
#pragma unroll
                    for (int m = 0; m < 4; m++)
                        acc[pm * 4 + m][pn * 2 + f] =
                            __builtin_amdgcn_mfma_f32_16x16x32_bf16(
                                av[m][kk], bv[f][kk],
                                acc[pm * 4 + m][pn * 2 + f], 0, 0, 0);
            __builtin_amdgcn_s_setprio(0);
            if (p < 3) __builtin_amdgcn_s_barrier();
        }
        __syncthreads();   // drains vmcnt (tile t+1 landed) + retires buffer reads
        db ^= 1;
    }
}

// ---------------------------------------------------------------------------
// GEMM1: S = a.b^T * temp; E = mask ? exp(S) : 0. Writes packed E (via full
// 256x256 LDS transpose, coalesced 512B rows) and packed ET (from regs),
// plus atomic l_row / l_col partials.
// Grid: 256 blocks, g = qq*16 + batch so all 16 blocks of one batch map to
// XCD batch%8 (a/b panels fetched ~once per XCD L2).
// ---------------------------------------------------------------------------
__global__ __launch_bounds__(512, 2) void k_gemm_attn(
    const unsigned short* __restrict__ a_bf, const unsigned short* __restrict__ b_bf,
    const int* __restrict__ mask_a, const int* __restrict__ mask_b,
    const float* __restrict__ temp_p,
    unsigned short* __restrict__ E, unsigned short* __restrict__ ET,
    float* __restrict__ l_row, float* __restrict__ l_col)
{
    __shared__ unsigned short lds[65536];        // 128 KiB: staging, then E tile

    const int g = blockIdx.x;
    const int batch = g & 15;
    const int qq = g >> 4;                       // 0..15
    const int i0 = (qq >> 2) * 256, j0 = (qq & 3) * 256;

    const unsigned short* A = a_bf + (size_t)batch * LA_ * H_ + (size_t)i0 * H_;
    const unsigned short* B = b_bf + (size_t)batch * LB_ * H_ + (size_t)j0 * H_;
    f32x4 acc[8][4];
#pragma unroll
    for (int x = 0; x < 8; x++)
#pragma unroll
        for (int y = 0; y < 4; y++) acc[x][y] = 0;

    gemm_core256(A, B, H_, H_, H_, lds, acc);

    const float temp = temp_p[0];
    const int t = threadIdx.x, w = t >> 6, lane = t & 63;
    const int wr = w >> 2, wc = w & 3, lm = lane & 15, q = lane >> 4;
    const int* map = mask_a + batch * LA_;
    const int* mbp = mask_b + batch * LB_;
    unsigned short* Ep  = E  + (size_t)batch * LA_ * LB_;
    unsigned short* ETp = ET + (size_t)batch * LB_ * LA_;
    float* lrp = l_row + batch * LA_;
    float* lcp = l_col + batch * LB_;

    int mb4[4];
#pragma unroll
    for (int fn = 0; fn < 4; fn++) mb4[fn] = mbp[j0 + wc * 64 + fn * 16 + lm];

    // transform acc -> e in place; write E tile into (now free) LDS with
    // chunk swizzle keyed on (il>>1)&15 (write conflict-free, row-read
    // bijective); store packed ET rows straight from regs.
#pragma unroll
    for (int fm = 0; fm < 8; fm++) {
        const int ilb = wr * 128 + fm * 16 + q * 4;
        int ma[4];
#pragma unroll
        for (int r = 0; r < 4; r++) ma[r] = map[i0 + ilb + r];
#pragma unroll
        for (int fn = 0; fn < 4; fn++) {
            const int jl = wc * 64 + fn * 16 + lm;
            ushort4 pk;
            unsigned short* pp = (unsigned short*)&pk;
#pragma unroll
            for (int r = 0; r < 4; r++) {
                const float e = (ma[r] && mb4[fn]) ? __expf(acc[fm][fn][r] * temp) : 0.0f;
                acc[fm][fn][r] = e;
                pp[r] = f2bf(e);
                const int il = ilb + r;
                lds[il * 256 + ((((jl >> 3) ^ ((il >> 1) & 15)) << 3) | (jl & 7))] = pp[r];
            }
            *(ushort4*)(ETp + (size_t)(j0 + jl) * LA_ + i0 + ilb) = pk;
        }
    }

    // l_row partials: sum over this block's 256 j's (per-wave 64-j partial)
#pragma unroll
    for (int fm = 0; fm < 8; fm++)
#pragma unroll
        for (int r = 0; r < 4; r++) {
            float s = acc[fm][0][r] + acc[fm][1][r] + acc[fm][2][r] + acc[fm][3][r];
            s += __shfl_xor(s, 1, 16); s += __shfl_xor(s, 2, 16);
            s += __shfl_xor(s, 4, 16); s += __shfl_xor(s, 8, 16);
            if (lm == 0) atomicAdd(&lrp[i0 + wr * 128 + fm * 16 + q * 4 + r], s);
        }
    // l_col partials: sum over this block's 256 i's (per-wave 128-i partial)
#pragma unroll
    for (int fn = 0; fn < 4; fn++) {
        float s = 0.0f;
#pragma unroll
        for (int fm = 0; fm < 8; fm++)
#pragma unroll
            for (int r = 0; r < 4; r++) s += acc[fm][fn][r];
        s += __shfl_xor(s, 16, 64); s += __shfl_xor(s, 32, 64);
        if (lane < 16) atomicAdd(&lcp[j0 + wc * 64 + fn * 16 + lm], s);
    }

    // packed E: coalesced 512B-row stores from the swizzled LDS tile
    __syncthreads();
#pragma unroll
    for (int rep = 0; rep < 16; rep++) {
        const int il = (t >> 5) + rep * 16;
        const int c = t & 31;
        const int phys = c ^ ((il >> 1) & 15);
        short8 v = *(const short8*)(lds + il * 256 + phys * 8);
        *(short8*)(Ep + (size_t)(i0 + il) * LB_ + j0 + c * 8) = v;
    }
}

// ---------------------------------------------------------------------------
// GEMM2+3 merged: zc<16 -> feature_a (E . bT^T), zc>=16 -> feature_b (ET.aT^T)
// Grid: 256 blocks, g = qq*32 + zc -> XCD zc%8 (A-tile/B-panel L2 sharing).
// ---------------------------------------------------------------------------
__global__ __launch_bounds__(512, 2) void k_gemm_feat(
    const unsigned short* __restrict__ E, const unsigned short* __restrict__ ET,
    const unsigned short* __restrict__ aT, const unsigned short* __restrict__ bT,
    const int* __restrict__ mask_a, const int* __restrict__ mask_b,
    const int* __restrict__ nA, const int* __restrict__ nB,
    const float* __restrict__ l_row, const float* __restrict__ l_col,
    const float* __restrict__ mean_a, const float* __restrict__ mean_b,
    float* __restrict__ out)
{
    __shared__ unsigned short lds[65536];

    const int g = blockIdx.x;
    const int zc = g & 31;
    const int qq = g >> 5;                       // 0..7
    const int n0 = (qq & 1) * 256, m0 = (qq >> 1) * 256;

    const int batch = zc & 15;
    const bool isA = zc < 16;
    const unsigned short* Amat = (isA ? E : ET) + (size_t)batch * 1024 * 1024;
    const unsigned short* Bm   = (isA ? bT : aT) + (size_t)batch * H_ * 1024;
    const int* mp   = (isA ? mask_a : mask_b) + batch * 1024;
    const int nn    = (isA ? nB : nA)[batch];
    const float* sp = (isA ? l_row : l_col) + batch * 1024;
    const float* mv = (isA ? mean_b : mean_a) + batch * H_;
    float* op = out + (isA ? (size_t)0 : (size_t)NB_ * LA_ * H_) + (size_t)batch * 1024 * H_;

    f32x4 acc[8][4];
#pragma unroll
    for (int x = 0; x < 8; x++)
#pragma unroll
        for (int y = 0; y < 4; y++) acc[x][y] = 0;

    gemm_core256(Amat + (size_t)m0 * 1024, Bm + (size_t)n0 * 1024,
                 1024, 1024, 1024, lds, acc);

    const int t = threadIdx.x, w = t >> 6, lane = t & 63;
    const int wr = w >> 2, wc = w & 3, lm = lane & 15, q = lane >> 4;

    float mval[4];
#pragma unroll
    for (int fn = 0; fn < 4; fn++) mval[fn] = mv[n0 + wc * 64 + fn * 16 + lm];

#pragma unroll
    for (int fm = 0; fm < 8; fm++) {
        const int ib = m0 + wr * 128 + fm * 16 + q * 4;
#pragma unroll
        for (int r = 0; r < 4; r++) {
            const int i = ib + r;
            const bool valid = (mp[i] != 0) && (nn > 0);
            const float inv = valid ? 1.0f / sp[i] : 0.0f;
#pragma unroll
            for (int fn = 0; fn < 4; fn++) {
                const int d = n0 + wc * 64 + fn * 16 + lm;
                op[(size_t)i * H_ + d] = valid ? acc[fm][fn][r] * inv : mval[fn];
            }
        }
    }
}

// ---------------------------------------------------------------------------
// prep (a and b merged): fp32 [1024][512] -> bf16 [1024][512] + bf16^T
// [512][1024], plus atomic per-batch column-mean partials.
// ---------------------------------------------------------------------------
__global__ __launch_bounds__(256) void k_prep(
    const float* __restrict__ a, const float* __restrict__ b,
    unsigned short* __restrict__ aN, unsigned short* __restrict__ bN,
    unsigned short* __restrict__ aT, unsigned short* __restrict__ bT,
    float* __restrict__ mean_a, float* __restrict__ mean_b)
{
    __shared__ unsigned short lds[64][68];
    __shared__ float smean[64];
    const int z = blockIdx.z;
    const int batch = z & 15, sel = z >> 4;
    const float* src = sel ? b : a;
    unsigned short* np = (sel ? bN : aN) + (size_t)batch * 1024 * H_;
    unsigned short* tp = (sel ? bT : aT) + (size_t)batch * H_ * 1024;
    float* mdst = (sel ? mean_b : mean_a) + batch * H_;
    const float* sp = src + (size_t)batch * 1024 * H_;

    const int d0 = blockIdx.x * 64, i0 = blockIdx.y * 64;
    const int t = threadIdx.x;
    if (t < 64) smean[t] = 0.0f;
    const int c4 = (t & 15) * 4;
#pragma unroll
    for (int it = 0; it < 4; it++) {
        const int r = (t >> 4) + it * 16;
        float4 v = *(const float4*)(sp + (size_t)(i0 + r) * H_ + d0 + c4);
        ushort4 u = make_ushort4(f2bf(v.x), f2bf(v.y), f2bf(v.z), f2bf(v.w));
        *(ushort4*)(np + (size_t)(i0 + r) * H_ + d0 + c4) = u;
        *(ushort4*)&lds[r][c4] = u;
    }
    __syncthreads();
#pragma unroll
    for (int it = 0; it < 4; it++) {
        const int dd = (t >> 4) + it * 16;
        const int i4 = (t & 15) * 4;
        ushort4 u = make_ushort4(lds[i4][dd], lds[i4 + 1][dd], lds[i4 + 2][dd], lds[i4 + 3][dd]);
        *(ushort4*)(tp + (size_t)(d0 + dd) * 1024 + i0 + i4) = u;
        atomicAdd(&smean[dd], bf2f(u.x) + bf2f(u.y) + bf2f(u.z) + bf2f(u.w));
    }
    __syncthreads();
    if (t < 64) atomicAdd(&mdst[d0 + t], smean[t] * (1.0f / 1024.0f));
}

// ---------------------------------------------------------------------------
// init: blocks 0..47 zero the 49152-float accumulator region (l_row, l_col,
// mean_a, mean_b); blocks 48..79 compute per-batch mask counts.
// ---------------------------------------------------------------------------
__global__ __launch_bounds__(256) void k_init(
    float* __restrict__ accum_zero,              // 49152 floats
    const int* __restrict__ mask_a, const int* __restrict__ mask_b,
    int* __restrict__ nA, int* __restrict__ nB)
{
    const int g = blockIdx.x, t = threadIdx.x;
    if (g < 48) {
        *(float4*)(accum_zero + (size_t)(g * 256 + t) * 4) = make_float4(0, 0, 0, 0);
        return;
    }
    const int sel = g - 48;                      // 0..31
    const int batch = sel & 15, which = sel >> 4;
    const int* m = (which ? mask_b : mask_a) + batch * 1024;
    int s = m[t] + m[t + 256] + m[t + 512] + m[t + 768];
    __shared__ int red[256];
    red[t] = s;
    __syncthreads();
    for (int off = 128; off; off >>= 1) {
        if (t < off) red[t] += red[t + off];
        __syncthreads();
    }
    if (t == 0) (which ? nB : nA)[batch] = red[0];
}

// ---------------------------------------------------------------------------
extern "C" void kernel_launch(void* const* d_in, const int* in_sizes, int n_in,
                              void* d_out, int out_size, void* d_ws, size_t ws_size,
                              hipStream_t stream)
{
    const float* a      = (const float*)d_in[0];
    const float* b      = (const float*)d_in[1];
    const int*   mask_a = (const int*)d_in[2];
    const int*   mask_b = (const int*)d_in[3];
    const float* temp   = (const float*)d_in[4];
    float* out = (float*)d_out;

    // workspace layout (~128.2 MiB)
    char* ws = (char*)d_ws;
    size_t off = 0;
    unsigned short* E    = (unsigned short*)(ws + off); off += (size_t)NB_ * LA_ * LB_ * 2;  // 32 MiB
    unsigned short* ET   = (unsigned short*)(ws + off); off += (size_t)NB_ * LB_ * LA_ * 2;  // 32 MiB
    unsigned short* a_bf = (unsigned short*)(ws + off); off += (size_t)NB_ * LA_ * H_ * 2;   // 16 MiB
    unsigned short* b_bf = (unsigned short*)(ws + off); off += (size_t)NB_ * LB_ * H_ * 2;   // 16 MiB
    unsigned short* aT   = (unsigned short*)(ws + off); off += (size_t)NB_ * H_ * LA_ * 2;   // 16 MiB
    unsigned short* bT   = (unsigned short*)(ws + off); off += (size_t)NB_ * H_ * LB_ * 2;   // 16 MiB
    float* l_row  = (float*)(ws + off); off += (size_t)NB_ * LA_ * 4;   // zeroed region start
    float* l_col  = (float*)(ws + off); off += (size_t)NB_ * LB_ * 4;
    float* mean_a = (float*)(ws + off); off += (size_t)NB_ * H_ * 4;
    float* mean_b = (float*)(ws + off); off += (size_t)NB_ * H_ * 4;
    int*   nA     = (int*)(ws + off); off += 64;
    int*   nB     = (int*)(ws + off); off += 64;

    // init: zero accumulators + mask counts
    k_init<<<dim3(80), 256, 0, stream>>>(l_row, mask_a, mask_b, nA, nB);

    k_prep<<<dim3(H_ / 64, 1024 / 64, 32), 256, 0, stream>>>(
        a, b, a_bf, b_bf, aT, bT, mean_a, mean_b);

    k_gemm_attn<<<dim3(256), 512, 0, stream>>>(
        a_bf, b_bf, mask_a, mask_b, temp, E, ET, l_row, l_col);

    k_gemm_feat<<<dim3(256), 512, 0, stream>>>(
        E, ET, aT, bT, mask_a, mask_b, nA, nB, l_row, l_col, mean_a, mean_b, out);
}

// Round 2
// 215.338 us; speedup vs baseline: 1.0616x; 1.0224x over previous
//
#include <hip/hip_runtime.h>
#include <hip/hip_bf16.h>

#define NB_ 16      // batches
#define LA_ 1024
#define LB_ 1024
#define H_  512

typedef __attribute__((ext_vector_type(8))) short short8;   // 8 bf16 = 4 VGPRs
typedef __attribute__((ext_vector_type(4))) float f32x4;    // MFMA C/D

using bf16 = __hip_bfloat16;

__device__ __forceinline__ float bf2f(unsigned short u) {
    union { unsigned int i; float f; } c; c.i = ((unsigned)u) << 16; return c.f;
}
__device__ __forceinline__ unsigned short f2bf(float f) {
    bf16 h = __float2bfloat16(f);
    return *(unsigned short*)&h;
}

__device__ __forceinline__ void load_lds16(const void* g, void* l) {
    __builtin_amdgcn_global_load_lds(
        (const __attribute__((address_space(1))) void*)g,
        (__attribute__((address_space(3))) void*)l, 16, 0, 0);
}

// ---------------------------------------------------------------------------
// MFMA GEMM core, 256x256 tile, BK=64, 8 waves (2Mx4N), double-buffered
// 128 KiB LDS, counted-vmcnt pipeline (T3/T4): never drain vmcnt to 0 in
// the main loop.
//
// Per K-tile, 4 phases (one C-quadrant each, 16 MFMA). Next tile's 8
// global_load_lds are spread 2-per-phase in the fixed order
//   p0: B[s0],B[s1]  p1: B[s2],B[s3]  p2: A[s0],A[s2]  p3: A[s1],A[s3]
// A wave's phase-0/1 ds_reads need only B[wc] + A[2wr] (first 6 issued);
// phase-2/3 need A[2wr+1] (last 2). Waits (after MFMA, before trailing
// barrier): vmcnt(4) at p1 (A-odd of CURRENT tile landed; 4 newer B' in
// flight), vmcnt(2) at p3 (B*,A0,A2 of NEXT tile landed; 2 newer A-odd in
// flight). vmem retires in order, so counts are exact.
//
// LDS tiles [256][64] bf16, 16B chunk slot XOR-swizzled by (row&7)
// (bank-conflict-free, measured 0 conflicts). db is compile-time via
// pair-unrolled tile steps.
// ---------------------------------------------------------------------------
template<int DB, int MODE>   // MODE 0 = steady (stage next), 1 = last tile
__device__ __forceinline__ void gemm_tile256(
    const unsigned short* __restrict__ gA, const unsigned short* __restrict__ gB,
    int lda, int ldb, size_t ko,
    unsigned short* lds, char* lA, char* lB,
    const int* aoff, const int* boff, f32x4 acc[8][4])
{
    const char* bA = (const char*)lds + DB * 32768;
    const char* bB = (const char*)lds + 65536 + DB * 32768;
    const int nxt = (DB ^ 1) * 32768;
    short8 av[4][2];
#pragma unroll
    for (int p = 0; p < 4; ++p) {
        const int pm = p >> 1, pn = p & 1;
        if (pn == 0) {                           // A-frags reused for pn=0,1
#pragma unroll
            for (int f = 0; f < 4; f++)
#pragma unroll
                for (int kk = 0; kk < 2; kk++)
                    av[f][kk] = *(const short8*)(bA + (aoff[pm * 4 + f] ^ (kk << 6)));
        }
        short8 bv[2][2];
#pragma unroll
        for (int f = 0; f < 2; f++)
#pragma unroll
            for (int kk = 0; kk < 2; kk++)
                bv[f][kk] = *(const short8*)(bB + (boff[pn * 2 + f] ^ (kk << 6)));
        if (MODE == 0) {                         // stage next tile, 2 per phase
            if (p == 0) {
                load_lds16(gB + ko,                       lB + nxt);
                load_lds16(gB + ko + (size_t)64 * ldb,    lB + nxt + 8192);
            } else if (p == 1) {
                load_lds16(gB + ko + (size_t)128 * ldb,   lB + nxt + 16384);
                load_lds16(gB + ko + (size_t)192 * ldb,   lB + nxt + 24576);
            } else if (p == 2) {
                load_lds16(gA + ko,                       lA + nxt);
                load_lds16(gA + ko + (size_t)128 * lda,   lA + nxt + 16384);
            } else {
                load_lds16(gA + ko + (size_t)64 * lda,    lA + nxt + 8192);
                load_lds16(gA + ko + (size_t)192 * lda,   lA + nxt + 24576);
            }
        }
        __builtin_amdgcn_s_barrier();
        __builtin_amdgcn_s_setprio(1);
#pragma unroll
        for (int kk = 0; kk < 2; kk++)
#pragma unroll
            for (int f = 0; f < 2; f++)
#pragma unroll
                for (int m = 0; m < 4; m++)
                    acc[pm * 4 + m][pn * 2 + f] =
                        __builtin_amdgcn_mfma_f32_16x16x32_bf16(
                            av[m][kk], bv[f][kk],
                            acc[pm * 4 + m][pn * 2 + f], 0, 0, 0);
        __builtin_amdgcn_s_setprio(0);
        if (p == 1) {
            if (MODE == 0) asm volatile("s_waitcnt vmcnt(4)" ::: "memory");
            else           asm volatile("s_waitcnt vmcnt(0)" ::: "memory");
        }
        if (p == 3 && MODE == 0) asm volatile("s_waitcnt vmcnt(2)" ::: "memory");
        if (p < 3 || MODE == 0) __builtin_amdgcn_s_barrier();
    }
}

__device__ __forceinline__ void gemm_core256(
    const unsigned short* __restrict__ A, const unsigned short* __restrict__ B,
    int lda, int ldb, int K,
    unsigned short* lds, f32x4 acc[8][4])
{
    const int t = threadIdx.x;
    const int w = t >> 6, lane = t & 63;
    const int wr = w >> 2, wc = w & 3;          // wave grid 2 (M) x 4 (N)
    const int lm = lane & 15, q = lane >> 4;

    // fragment LDS byte offsets for kk=0; kk=1 is addr ^ 64 (chunk bit2 flip)
    int aoff[8], boff[4];
#pragma unroll
    for (int f = 0; f < 8; f++) {
        const int ra = wr * 128 + f * 16 + lm;
        aoff[f] = ra * 128 + ((q ^ (ra & 7)) << 4);
    }
#pragma unroll
    for (int f = 0; f < 4; f++) {
        const int rb = wc * 64 + f * 16 + lm;
        boff[f] = rb * 128 + ((q ^ (rb & 7)) << 4);
    }

    // staging addresses: load s covers rows [s*64,(s+1)*64); per wave 8 rows
    // x 128 B linear; source chunk pre-swizzled so LDS slot c holds global
    // chunk c ^ (row&7); row&7 == lane>>3 here.
    const int rstep = w * 8 + (lane >> 3);
    const int sc = (lane & 7) ^ (lane >> 3);
    const unsigned short* gA = A + (size_t)rstep * lda + sc * 8;
    const unsigned short* gB = B + (size_t)rstep * ldb + sc * 8;
    char* lA = (char*)lds + w * 1024;            // A buffers: bytes [0,65536)
    char* lB = (char*)lds + 65536 + w * 1024;    // B buffers: bytes [65536,131072)
    const int NT = K >> 6;

    // prologue: stage tile 0 into buffer 0, order B0,B1,B2,B3,A0,A2,A1,A3
    load_lds16(gB,                       lB);
    load_lds16(gB + (size_t)64 * ldb,    lB + 8192);
    load_lds16(gB + (size_t)128 * ldb,   lB + 16384);
    load_lds16(gB + (size_t)192 * ldb,   lB + 24576);
    load_lds16(gA,                       lA);
    load_lds16(gA + (size_t)128 * lda,   lA + 16384);
    load_lds16(gA + (size_t)64 * lda,    lA + 8192);
    load_lds16(gA + (size_t)192 * lda,   lA + 24576);
    asm volatile("s_waitcnt vmcnt(2)" ::: "memory");
    __builtin_amdgcn_s_barrier();

    int kt = 0;
    for (; kt + 2 < NT; kt += 2) {
        gemm_tile256<0, 0>(gA, gB, lda, ldb, (size_t)(kt + 1) * 64,
                           lds, lA, lB, aoff, boff, acc);
        gemm_tile256<1, 0>(gA, gB, lda, ldb, (size_t)(kt + 2) * 64,
                           lds, lA, lB, aoff, boff, acc);
    }
    // kt == NT-2 (NT even): stage last tile, then epilogue tile (no staging)
    gemm_tile256<0, 0>(gA, gB, lda, ldb, (size_t)(NT - 1) * 64,
                       lds, lA, lB, aoff, boff, acc);
    gemm_tile256<1, 1>(gA, gB, lda, ldb, 0, lds, lA, lB, aoff, boff, acc);
    __syncthreads();   // retire all LDS reads before callers reuse LDS
}

// ---------------------------------------------------------------------------
// GEMM1: S = a.b^T * temp; E = mask ? exp(S) : 0. Writes packed E (via full
// 256x256 LDS transpose, coalesced 512B rows) and packed ET (from regs),
// plus atomic l_row / l_col partials.
// Grid: 256 blocks, g = qq*16 + batch so all 16 blocks of one batch map to
// XCD batch%8 (a/b panels fetched ~once per XCD L2).
// ---------------------------------------------------------------------------
__global__ __launch_bounds__(512, 2) void k_gemm_attn(
    const unsigned short* __restrict__ a_bf, const unsigned short* __restrict__ b_bf,
    const int* __restrict__ mask_a, const int* __restrict__ mask_b,
    const float* __restrict__ temp_p,
    unsigned short* __restrict__ E, unsigned short* __restrict__ ET,
    float* __restrict__ l_row, float* __restrict__ l_col)
{
    __shared__ unsigned short lds[65536];        // 128 KiB: staging, then E tile

    const int g = blockIdx.x;
    const int batch = g & 15;
    const int qq = g >> 4;                       // 0..15
    const int i0 = (qq >> 2) * 256, j0 = (qq & 3) * 256;

    const unsigned short* A = a_bf + (size_t)batch * LA_ * H_ + (size_t)i0 * H_;
    const unsigned short* B = b_bf + (size_t)batch * LB_ * H_ + (size_t)j0 * H_;
    f32x4 acc[8][4];
#pragma unroll
    for (int x = 0; x < 8; x++)
#pragma unroll
        for (int y = 0; y < 4; y++) acc[x][y] = 0;

    gemm_core256(A, B, H_, H_, H_, lds, acc);

    const float temp = temp_p[0];
    const int t = threadIdx.x, w = t >> 6, lane = t & 63;
    const int wr = w >> 2, wc = w & 3, lm = lane & 15, q = lane >> 4;
    const int* map = mask_a + batch * LA_;
    const int* mbp = mask_b + batch * LB_;
    unsigned short* Ep  = E  + (size_t)batch * LA_ * LB_;
    unsigned short* ETp = ET + (size_t)batch * LB_ * LA_;
    float* lrp = l_row + batch * LA_;
    float* lcp = l_col + batch * LB_;

    int mb4[4];
#pragma unroll
    for (int fn = 0; fn < 4; fn++) mb4[fn] = mbp[j0 + wc * 64 + fn * 16 + lm];

    // transform acc -> e in place; write E tile into (now free) LDS with
    // chunk swizzle keyed on (il>>1)&15 (write conflict-free, row-read
    // bijective); store packed ET rows straight from regs.
#pragma unroll
    for (int fm = 0; fm < 8; fm++) {
        const int ilb = wr * 128 + fm * 16 + q * 4;
        int ma[4];
#pragma unroll
        for (int r = 0; r < 4; r++) ma[r] = map[i0 + ilb + r];
#pragma unroll
        for (int fn = 0; fn < 4; fn++) {
            const int jl = wc * 64 + fn * 16 + lm;
            ushort4 pk;
            unsigned short* pp = (unsigned short*)&pk;
#pragma unroll
            for (int r = 0; r < 4; r++) {
                const float e = (ma[r] && mb4[fn]) ? __expf(acc[fm][fn][r] * temp) : 0.0f;
                acc[fm][fn][r] = e;
                pp[r] = f2bf(e);
                const int il = ilb + r;
                lds[il * 256 + ((((jl >> 3) ^ ((il >> 1) & 15)) << 3) | (jl & 7))] = pp[r];
            }
            *(ushort4*)(ETp + (size_t)(j0 + jl) * LA_ + i0 + ilb) = pk;
        }
    }

    // l_row partials: sum over this block's 256 j's (per-wave 64-j partial)
#pragma unroll
    for (int fm = 0; fm < 8; fm++)
#pragma unroll
        for (int r = 0; r < 4; r++) {
            float s = acc[fm][0][r] + acc[fm][1][r] + acc[fm][2][r] + acc[fm][3][r];
            s += __shfl_xor(s, 1, 16); s += __shfl_xor(s, 2, 16);
            s += __shfl_xor(s, 4, 16); s += __shfl_xor(s, 8, 16);
            if (lm == 0) atomicAdd(&lrp[i0 + wr * 128 + fm * 16 + q * 4 + r], s);
        }
    // l_col partials: sum over this block's 256 i's (per-wave 128-i partial)
#pragma unroll
    for (int fn = 0; fn < 4; fn++) {
        float s = 0.0f;
#pragma unroll
        for (int fm = 0; fm < 8; fm++)
#pragma unroll
            for (int r = 0; r < 4; r++) s += acc[fm][fn][r];
        s += __shfl_xor(s, 16, 64); s += __shfl_xor(s, 32, 64);
        if (lane < 16) atomicAdd(&lcp[j0 + wc * 64 + fn * 16 + lm], s);
    }

    // packed E: coalesced 512B-row stores from the swizzled LDS tile
    __syncthreads();
#pragma unroll
    for (int rep = 0; rep < 16; rep++) {
        const int il = (t >> 5) + rep * 16;
        const int c = t & 31;
        const int phys = c ^ ((il >> 1) & 15);
        short8 v = *(const short8*)(lds + il * 256 + phys * 8);
        *(short8*)(Ep + (size_t)(i0 + il) * LB_ + j0 + c * 8) = v;
    }
}

// ---------------------------------------------------------------------------
// GEMM2+3 merged: zc<16 -> feature_a (E . bT^T), zc>=16 -> feature_b (ET.aT^T)
// Grid: 256 blocks, g = qq*32 + zc -> XCD zc%8 (A-tile/B-panel L2 sharing).
// ---------------------------------------------------------------------------
__global__ __launch_bounds__(512, 2) void k_gemm_feat(
    const unsigned short* __restrict__ E, const unsigned short* __restrict__ ET,
    const unsigned short* __restrict__ aT, const unsigned short* __restrict__ bT,
    const int* __restrict__ mask_a, const int* __restrict__ mask_b,
    const int* __restrict__ nA, const int* __restrict__ nB,
    const float* __restrict__ l_row, const float* __restrict__ l_col,
    const float* __restrict__ mean_a, const float* __restrict__ mean_b,
    float* __restrict__ out)
{
    __shared__ unsigned short lds[65536];

    const int g = blockIdx.x;
    const int zc = g & 31;
    const int qq = g >> 5;                       // 0..7
    const int n0 = (qq & 1) * 256, m0 = (qq >> 1) * 256;

    const int batch = zc & 15;
    const bool isA = zc < 16;
    const unsigned short* Amat = (isA ? E : ET) + (size_t)batch * 1024 * 1024;
    const unsigned short* Bm   = (isA ? bT : aT) + (size_t)batch * H_ * 1024;
    const int* mp   = (isA ? mask_a : mask_b) + batch * 1024;
    const int nn    = (isA ? nB : nA)[batch];
    const float* sp = (isA ? l_row : l_col) + batch * 1024;
    const float* mv = (isA ? mean_b : mean_a) + batch * H_;
    float* op = out + (isA ? (size_t)0 : (size_t)NB_ * LA_ * H_) + (size_t)batch * 1024 * H_;

    f32x4 acc[8][4];
#pragma unroll
    for (int x = 0; x < 8; x++)
#pragma unroll
        for (int y = 0; y < 4; y++) acc[x][y] = 0;

    gemm_core256(Amat + (size_t)m0 * 1024, Bm + (size_t)n0 * 1024,
                 1024, 1024, 1024, lds, acc);

    const int t = threadIdx.x, w = t >> 6, lane = t & 63;
    const int wr = w >> 2, wc = w & 3, lm = lane & 15, q = lane >> 4;

    float mval[4];
#pragma unroll
    for (int fn = 0; fn < 4; fn++) mval[fn] = mv[n0 + wc * 64 + fn * 16 + lm];

#pragma unroll
    for (int fm = 0; fm < 8; fm++) {
        const int ib = m0 + wr * 128 + fm * 16 + q * 4;
#pragma unroll
        for (int r = 0; r < 4; r++) {
            const int i = ib + r;
            const bool valid = (mp[i] != 0) && (nn > 0);
            const float inv = valid ? 1.0f / sp[i] : 0.0f;
#pragma unroll
            for (int fn = 0; fn < 4; fn++) {
                const int d = n0 + wc * 64 + fn * 16 + lm;
                op[(size_t)i * H_ + d] = valid ? acc[fm][fn][r] * inv : mval[fn];
            }
        }
    }
}

// ---------------------------------------------------------------------------
// prep (a and b merged): fp32 [1024][512] -> bf16 [1024][512] + bf16^T
// [512][1024], plus atomic per-batch column-mean partials.
// ---------------------------------------------------------------------------
__global__ __launch_bounds__(256) void k_prep(
    const float* __restrict__ a, const float* __restrict__ b,
    unsigned short* __restrict__ aN, unsigned short* __restrict__ bN,
    unsigned short* __restrict__ aT, unsigned short* __restrict__ bT,
    float* __restrict__ mean_a, float* __restrict__ mean_b)
{
    __shared__ unsigned short lds[64][68];
    __shared__ float smean[64];
    const int z = blockIdx.z;
    const int batch = z & 15, sel = z >> 4;
    const float* src = sel ? b : a;
    unsigned short* np = (sel ? bN : aN) + (size_t)batch * 1024 * H_;
    unsigned short* tp = (sel ? bT : aT) + (size_t)batch * H_ * 1024;
    float* mdst = (sel ? mean_b : mean_a) + batch * H_;
    const float* sp = src + (size_t)batch * 1024 * H_;

    const int d0 = blockIdx.x * 64, i0 = blockIdx.y * 64;
    const int t = threadIdx.x;
    if (t < 64) smean[t] = 0.0f;
    const int c4 = (t & 15) * 4;
#pragma unroll
    for (int it = 0; it < 4; it++) {
        const int r = (t >> 4) + it * 16;
        float4 v = *(const float4*)(sp + (size_t)(i0 + r) * H_ + d0 + c4);
        ushort4 u = make_ushort4(f2bf(v.x), f2bf(v.y), f2bf(v.z), f2bf(v.w));
        *(ushort4*)(np + (size_t)(i0 + r) * H_ + d0 + c4) = u;
        *(ushort4*)&lds[r][c4] = u;
    }
    __syncthreads();
#pragma unroll
    for (int it = 0; it < 4; it++) {
        const int dd = (t >> 4) + it * 16;
        const int i4 = (t & 15) * 4;
        ushort4 u = make_ushort4(lds[i4][dd], lds[i4 + 1][dd], lds[i4 + 2][dd], lds[i4 + 3][dd]);
        *(ushort4*)(tp + (size_t)(d0 + dd) * 1024 + i0 + i4) = u;
        atomicAdd(&smean[dd], bf2f(u.x) + bf2f(u.y) + bf2f(u.z) + bf2f(u.w));
    }
    __syncthreads();
    if (t < 64) atomicAdd(&mdst[d0 + t], smean[t] * (1.0f / 1024.0f));
}

// ---------------------------------------------------------------------------
// init: blocks 0..47 zero the 49152-float accumulator region (l_row, l_col,
// mean_a, mean_b); blocks 48..79 compute per-batch mask counts.
// ---------------------------------------------------------------------------
__global__ __launch_bounds__(256) void k_init(
    float* __restrict__ accum_zero,              // 49152 floats
    const int* __restrict__ mask_a, const int* __restrict__ mask_b,
    int* __restrict__ nA, int* __restrict__ nB)
{
    const int g = blockIdx.x, t = threadIdx.x;
    if (g < 48) {
        *(float4*)(accum_zero + (size_t)(g * 256 + t) * 4) = make_float4(0, 0, 0, 0);
        return;
    }
    const int sel = g - 48;                      // 0..31
    const int batch = sel & 15, which = sel >> 4;
    const int* m = (which ? mask_b : mask_a) + batch * 1024;
    int s = m[t] + m[t + 256] + m[t + 512] + m[t + 768];
    __shared__ int red[256];
    red[t] = s;
    __syncthreads();
    for (int off = 128; off; off >>= 1) {
        if (t < off) red[t] += red[t + off];
        __syncthreads();
    }
    if (t == 0) (which ? nB : nA)[batch] = red[0];
}

// ---------------------------------------------------------------------------
extern "C" void kernel_launch(void* const* d_in, const int* in_sizes, int n_in,
                              void* d_out, int out_size, void* d_ws, size_t ws_size,
                              hipStream_t stream)
{
    const float* a      = (const float*)d_in[0];
    const float* b      = (const float*)d_in[1];
    const int*   mask_a = (const int*)d_in[2];
    const int*   mask_b = (const int*)d_in[3];
    const float* temp   = (const float*)d_in[4];
    float* out = (float*)d_out;

    // workspace layout (~128.2 MiB)
    char* ws = (char*)d_ws;
    size_t off = 0;
    unsigned short* E    = (unsigned short*)(ws + off); off += (size_t)NB_ * LA_ * LB_ * 2;  // 32 MiB
    unsigned short* ET   = (unsigned short*)(ws + off); off += (size_t)NB_ * LB_ * LA_ * 2;  // 32 MiB
    unsigned short* a_bf = (unsigned short*)(ws + off); off += (size_t)NB_ * LA_ * H_ * 2;   // 16 MiB
    unsigned short* b_bf = (unsigned short*)(ws + off); off += (size_t)NB_ * LB_ * H_ * 2;   // 16 MiB
    unsigned short* aT   = (unsigned short*)(ws + off); off += (size_t)NB_ * H_ * LA_ * 2;   // 16 MiB
    unsigned short* bT   = (unsigned short*)(ws + off); off += (size_t)NB_ * H_ * LB_ * 2;   // 16 MiB
    float* l_row  = (float*)(ws + off); off += (size_t)NB_ * LA_ * 4;   // zeroed region start
    float* l_col  = (float*)(ws + off); off += (size_t)NB_ * LB_ * 4;
    float* mean_a = (float*)(ws + off); off += (size_t)NB_ * H_ * 4;
    float* mean_b = (float*)(ws + off); off += (size_t)NB_ * H_ * 4;
    int*   nA     = (int*)(ws + off); off += 64;
    int*   nB     = (int*)(ws + off); off += 64;

    // init: zero accumulators + mask counts
    k_init<<<dim3(80), 256, 0, stream>>>(l_row, mask_a, mask_b, nA, nB);

    k_prep<<<dim3(H_ / 64, 1024 / 64, 32), 256, 0, stream>>>(
        a, b, a_bf, b_bf, aT, bT, mean_a, mean_b);

    k_gemm_attn<<<dim3(256), 512, 0, stream>>>(
        a_bf, b_bf, mask_a, mask_b, temp, E, ET, l_row, l_col);

    k_gemm_feat<<<dim3(256), 512, 0, stream>>>(
        E, ET, aT, bT, mask_a, mask_b, nA, nB, l_row, l_col, mean_a, mean_b, out);
}

// Round 3
// 203.066 us; speedup vs baseline: 1.1257x; 1.0604x over previous
//
#include <hip/hip_runtime.h>
#include <hip/hip_bf16.h>

#define NB_ 16      // batches
#define LA_ 1024
#define LB_ 1024
#define H_  512

typedef __attribute__((ext_vector_type(8))) short short8;   // 8 bf16 = 4 VGPRs
typedef __attribute__((ext_vector_type(4))) float f32x4;    // MFMA C/D

using bf16 = __hip_bfloat16;

__device__ __forceinline__ float bf2f(unsigned short u) {
    union { unsigned int i; float f; } c; c.i = ((unsigned)u) << 16; return c.f;
}
__device__ __forceinline__ unsigned short f2bf(float f) {
    bf16 h = __float2bfloat16(f);
    return *(unsigned short*)&h;
}

__device__ __forceinline__ void load_lds16(const void* g, void* l) {
    __builtin_amdgcn_global_load_lds(
        (const __attribute__((address_space(1))) void*)g,
        (__attribute__((address_space(3))) void*)l, 16, 0, 0);
}

// ---------------------------------------------------------------------------
// MFMA GEMM core, 256x256 tile, BK=64, 8 waves (2Mx4N), double-buffered
// 128 KiB LDS. Two schedules (template<SCHED>):
//   SCHED=0 (counted): loads spread 2/phase, s_waitcnt vmcnt(4)/(2), never
//     drain to 0 in the loop.  [R2: big win for k_gemm_feat]
//   SCHED=1 (drain): all 8 next-tile loads at tile top, per-tile
//     __syncthreads drain.     [R1: k_gemm_attn ran <=48.6 us; the counted
//     schedule regressed attn to 73 us -> revert attn only]
// LDS tiles [256][64] bf16, 16B chunk slot XOR-swizzled by (row&7)
// (bank-conflict-free, measured 0 conflicts). db compile-time via
// pair-unrolled tile steps.
// ---------------------------------------------------------------------------
template<int DB, int MODE>   // MODE 0 = steady (stage next), 1 = last tile
__device__ __forceinline__ void gemm_tile_cnt(
    const unsigned short* __restrict__ gA, const unsigned short* __restrict__ gB,
    int lda, int ldb, size_t ko,
    unsigned short* lds, char* lA, char* lB,
    const int* aoff, const int* boff, f32x4 acc[8][4])
{
    const char* bA = (const char*)lds + DB * 32768;
    const char* bB = (const char*)lds + 65536 + DB * 32768;
    const int nxt = (DB ^ 1) * 32768;
    short8 av[4][2];
#pragma unroll
    for (int p = 0; p < 4; ++p) {
        const int pm = p >> 1, pn = p & 1;
        if (pn == 0) {                           // A-frags reused for pn=0,1
#pragma unroll
            for (int f = 0; f < 4; f++)
#pragma unroll
                for (int kk = 0; kk < 2; kk++)
                    av[f][kk] = *(const short8*)(bA + (aoff[pm * 4 + f] ^ (kk << 6)));
        }
        short8 bv[2][2];
#pragma unroll
        for (int f = 0; f < 2; f++)
#pragma unroll
            for (int kk = 0; kk < 2; kk++)
                bv[f][kk] = *(const short8*)(bB + (boff[pn * 2 + f] ^ (kk << 6)));
        if (MODE == 0) {                         // stage next tile, 2 per phase
            if (p == 0) {
                load_lds16(gB + ko,                       lB + nxt);
                load_lds16(gB + ko + (size_t)64 * ldb,    lB + nxt + 8192);
            } else if (p == 1) {
                load_lds16(gB + ko + (size_t)128 * ldb,   lB + nxt + 16384);
                load_lds16(gB + ko + (size_t)192 * ldb,   lB + nxt + 24576);
            } else if (p == 2) {
                load_lds16(gA + ko,                       lA + nxt);
                load_lds16(gA + ko + (size_t)128 * lda,   lA + nxt + 16384);
            } else {
                load_lds16(gA + ko + (size_t)64 * lda,    lA + nxt + 8192);
                load_lds16(gA + ko + (size_t)192 * lda,   lA + nxt + 24576);
            }
        }
        __builtin_amdgcn_s_barrier();
        __builtin_amdgcn_s_setprio(1);
#pragma unroll
        for (int kk = 0; kk < 2; kk++)
#pragma unroll
            for (int f = 0; f < 2; f++)
#pragma unroll
                for (int m = 0; m < 4; m++)
                    acc[pm * 4 + m][pn * 2 + f] =
                        __builtin_amdgcn_mfma_f32_16x16x32_bf16(
                            av[m][kk], bv[f][kk],
                            acc[pm * 4 + m][pn * 2 + f], 0, 0, 0);
        __builtin_amdgcn_s_setprio(0);
        if (p == 1) {
            if (MODE == 0) asm volatile("s_waitcnt vmcnt(4)" ::: "memory");
            else           asm volatile("s_waitcnt vmcnt(0)" ::: "memory");
        }
        if (p == 3 && MODE == 0) asm volatile("s_waitcnt vmcnt(2)" ::: "memory");
        if (p < 3 || MODE == 0) __builtin_amdgcn_s_barrier();
    }
}

template<int DB, int MODE>   // drain-style tile (R1 schedule)
__device__ __forceinline__ void gemm_tile_drn(
    const unsigned short* __restrict__ gA, const unsigned short* __restrict__ gB,
    int lda, int ldb, size_t ko,
    unsigned short* lds, char* lA, char* lB,
    const int* aoff, const int* boff, f32x4 acc[8][4])
{
    const char* bA = (const char*)lds + DB * 32768;
    const char* bB = (const char*)lds + 65536 + DB * 32768;
    const int nxt = (DB ^ 1) * 32768;
    if (MODE == 0) {                             // stage next tile, all 8 up front
#pragma unroll
        for (int s = 0; s < 4; s++) {
            load_lds16(gA + ko + (size_t)(s * 64) * lda, lA + nxt + s * 8192);
            load_lds16(gB + ko + (size_t)(s * 64) * ldb, lB + nxt + s * 8192);
        }
    }
    short8 av[4][2];
#pragma unroll
    for (int p = 0; p < 4; ++p) {
        const int pm = p >> 1, pn = p & 1;
        if (pn == 0) {
#pragma unroll
            for (int f = 0; f < 4; f++)
#pragma unroll
                for (int kk = 0; kk < 2; kk++)
                    av[f][kk] = *(const short8*)(bA + (aoff[pm * 4 + f] ^ (kk << 6)));
        }
        short8 bv[2][2];
#pragma unroll
        for (int f = 0; f < 2; f++)
#pragma unroll
            for (int kk = 0; kk < 2; kk++)
                bv[f][kk] = *(const short8*)(bB + (boff[pn * 2 + f] ^ (kk << 6)));
        __builtin_amdgcn_s_barrier();
        __builtin_amdgcn_s_setprio(1);
#pragma unroll
        for (int kk = 0; kk < 2; kk++)
#pragma unroll
            for (int f = 0; f < 2; f++)
#pragma unroll
                for (int m = 0; m < 4; m++)
                    acc[pm * 4 + m][pn * 2 + f] =
                        __builtin_amdgcn_mfma_f32_16x16x32_bf16(
                            av[m][kk], bv[f][kk],
                            acc[pm * 4 + m][pn * 2 + f], 0, 0, 0);
        __builtin_amdgcn_s_setprio(0);
        if (p < 3) __builtin_amdgcn_s_barrier();
    }
    __syncthreads();                             // drain vmcnt + retire reads
}

template<int SCHED>
__device__ __forceinline__ void gemm_core256(
    const unsigned short* __restrict__ A, const unsigned short* __restrict__ B,
    int lda, int ldb, int K,
    unsigned short* lds, f32x4 acc[8][4])
{
    const int t = threadIdx.x;
    const int w = t >> 6, lane = t & 63;
    const int wr = w >> 2, wc = w & 3;          // wave grid 2 (M) x 4 (N)
    const int lm = lane & 15, q = lane >> 4;

    // fragment LDS byte offsets for kk=0; kk=1 is addr ^ 64 (chunk bit2 flip)
    int aoff[8], boff[4];
#pragma unroll
    for (int f = 0; f < 8; f++) {
        const int ra = wr * 128 + f * 16 + lm;
        aoff[f] = ra * 128 + ((q ^ (ra & 7)) << 4);
    }
#pragma unroll
    for (int f = 0; f < 4; f++) {
        const int rb = wc * 64 + f * 16 + lm;
        boff[f] = rb * 128 + ((q ^ (rb & 7)) << 4);
    }

    // staging addresses: load s covers rows [s*64,(s+1)*64); per wave 8 rows
    // x 128 B linear; source chunk pre-swizzled so LDS slot c holds global
    // chunk c ^ (row&7); row&7 == lane>>3 here.
    const int rstep = w * 8 + (lane >> 3);
    const int sc = (lane & 7) ^ (lane >> 3);
    const unsigned short* gA = A + (size_t)rstep * lda + sc * 8;
    const unsigned short* gB = B + (size_t)rstep * ldb + sc * 8;
    char* lA = (char*)lds + w * 1024;            // A buffers: bytes [0,65536)
    char* lB = (char*)lds + 65536 + w * 1024;    // B buffers: bytes [65536,131072)
    const int NT = K >> 6;

    if (SCHED == 0) {
        // prologue order B0,B1,B2,B3,A0,A2,A1,A3 matches counted waits
        load_lds16(gB,                       lB);
        load_lds16(gB + (size_t)64 * ldb,    lB + 8192);
        load_lds16(gB + (size_t)128 * ldb,   lB + 16384);
        load_lds16(gB + (size_t)192 * ldb,   lB + 24576);
        load_lds16(gA,                       lA);
        load_lds16(gA + (size_t)128 * lda,   lA + 16384);
        load_lds16(gA + (size_t)64 * lda,    lA + 8192);
        load_lds16(gA + (size_t)192 * lda,   lA + 24576);
        asm volatile("s_waitcnt vmcnt(2)" ::: "memory");
        __builtin_amdgcn_s_barrier();
        int kt = 0;
        for (; kt + 2 < NT; kt += 2) {
            gemm_tile_cnt<0, 0>(gA, gB, lda, ldb, (size_t)(kt + 1) * 64,
                                lds, lA, lB, aoff, boff, acc);
            gemm_tile_cnt<1, 0>(gA, gB, lda, ldb, (size_t)(kt + 2) * 64,
                                lds, lA, lB, aoff, boff, acc);
        }
        gemm_tile_cnt<0, 0>(gA, gB, lda, ldb, (size_t)(NT - 1) * 64,
                            lds, lA, lB, aoff, boff, acc);
        gemm_tile_cnt<1, 1>(gA, gB, lda, ldb, 0, lds, lA, lB, aoff, boff, acc);
    } else {
#pragma unroll
        for (int s = 0; s < 4; s++) {
            load_lds16(gA + (size_t)(s * 64) * lda, lA + s * 8192);
            load_lds16(gB + (size_t)(s * 64) * ldb, lB + s * 8192);
        }
        __syncthreads();                         // full drain before first reads
        int kt = 0;
        for (; kt + 2 < NT; kt += 2) {
            gemm_tile_drn<0, 0>(gA, gB, lda, ldb, (size_t)(kt + 1) * 64,
                                lds, lA, lB, aoff, boff, acc);
            gemm_tile_drn<1, 0>(gA, gB, lda, ldb, (size_t)(kt + 2) * 64,
                                lds, lA, lB, aoff, boff, acc);
        }
        gemm_tile_drn<0, 0>(gA, gB, lda, ldb, (size_t)(NT - 1) * 64,
                            lds, lA, lB, aoff, boff, acc);
        gemm_tile_drn<1, 1>(gA, gB, lda, ldb, 0, lds, lA, lB, aoff, boff, acc);
    }
    __syncthreads();   // retire all LDS reads before callers reuse LDS
}

// ---------------------------------------------------------------------------
// GEMM1: S = a.b^T * temp; E = mask ? exp(S) : 0. Writes packed E (via full
// 256x256 LDS transpose, coalesced 512B rows) and packed ET (from regs),
// plus atomic l_row / l_col partials.
// Grid: 256 blocks, g = qq*16 + batch -> XCD batch%8 (panel L2 locality).
// Uses drain schedule (SCHED=1): counted schedule regressed attn 48->73 us.
// ---------------------------------------------------------------------------
__global__ __launch_bounds__(512, 2) void k_gemm_attn(
    const unsigned short* __restrict__ a_bf, const unsigned short* __restrict__ b_bf,
    const int* __restrict__ mask_a, const int* __restrict__ mask_b,
    const float* __restrict__ temp_p,
    unsigned short* __restrict__ E, unsigned short* __restrict__ ET,
    float* __restrict__ l_row, float* __restrict__ l_col)
{
    __shared__ unsigned short lds[65536];        // 128 KiB: staging, then E tile

    const int g = blockIdx.x;
    const int batch = g & 15;
    const int qq = g >> 4;                       // 0..15
    const int i0 = (qq >> 2) * 256, j0 = (qq & 3) * 256;

    const unsigned short* A = a_bf + (size_t)batch * LA_ * H_ + (size_t)i0 * H_;
    const unsigned short* B = b_bf + (size_t)batch * LB_ * H_ + (size_t)j0 * H_;
    f32x4 acc[8][4];
#pragma unroll
    for (int x = 0; x < 8; x++)
#pragma unroll
        for (int y = 0; y < 4; y++) acc[x][y] = 0;

    gemm_core256<1>(A, B, H_, H_, H_, lds, acc);

    const float temp = temp_p[0];
    const int t = threadIdx.x, w = t >> 6, lane = t & 63;
    const int wr = w >> 2, wc = w & 3, lm = lane & 15, q = lane >> 4;
    const int* map = mask_a + batch * LA_;
    const int* mbp = mask_b + batch * LB_;
    unsigned short* Ep  = E  + (size_t)batch * LA_ * LB_;
    unsigned short* ETp = ET + (size_t)batch * LB_ * LA_;
    float* lrp = l_row + batch * LA_;
    float* lcp = l_col + batch * LB_;

    int mb4[4];
#pragma unroll
    for (int fn = 0; fn < 4; fn++) mb4[fn] = mbp[j0 + wc * 64 + fn * 16 + lm];

    // transform acc -> e in place; write E tile into (now free) LDS with
    // chunk swizzle keyed on (il>>1)&15 (write conflict-free, row-read
    // bijective); store packed ET rows straight from regs.
#pragma unroll
    for (int fm = 0; fm < 8; fm++) {
        const int ilb = wr * 128 + fm * 16 + q * 4;
        int ma[4];
#pragma unroll
        for (int r = 0; r < 4; r++) ma[r] = map[i0 + ilb + r];
#pragma unroll
        for (int fn = 0; fn < 4; fn++) {
            const int jl = wc * 64 + fn * 16 + lm;
            ushort4 pk;
            unsigned short* pp = (unsigned short*)&pk;
#pragma unroll
            for (int r = 0; r < 4; r++) {
                const float e = (ma[r] && mb4[fn]) ? __expf(acc[fm][fn][r] * temp) : 0.0f;
                acc[fm][fn][r] = e;
                pp[r] = f2bf(e);
                const int il = ilb + r;
                lds[il * 256 + ((((jl >> 3) ^ ((il >> 1) & 15)) << 3) | (jl & 7))] = pp[r];
            }
            *(ushort4*)(ETp + (size_t)(j0 + jl) * LA_ + i0 + ilb) = pk;
        }
    }

    // l_row partials: sum over this block's 256 j's (per-wave 64-j partial)
#pragma unroll
    for (int fm = 0; fm < 8; fm++)
#pragma unroll
        for (int r = 0; r < 4; r++) {
            float s = acc[fm][0][r] + acc[fm][1][r] + acc[fm][2][r] + acc[fm][3][r];
            s += __shfl_xor(s, 1, 16); s += __shfl_xor(s, 2, 16);
            s += __shfl_xor(s, 4, 16); s += __shfl_xor(s, 8, 16);
            if (lm == 0) atomicAdd(&lrp[i0 + wr * 128 + fm * 16 + q * 4 + r], s);
        }
    // l_col partials: sum over this block's 256 i's (per-wave 128-i partial)
#pragma unroll
    for (int fn = 0; fn < 4; fn++) {
        float s = 0.0f;
#pragma unroll
        for (int fm = 0; fm < 8; fm++)
#pragma unroll
            for (int r = 0; r < 4; r++) s += acc[fm][fn][r];
        s += __shfl_xor(s, 16, 64); s += __shfl_xor(s, 32, 64);
        if (lane < 16) atomicAdd(&lcp[j0 + wc * 64 + fn * 16 + lm], s);
    }

    // packed E: coalesced 512B-row stores from the swizzled LDS tile
    __syncthreads();
#pragma unroll
    for (int rep = 0; rep < 16; rep++) {
        const int il = (t >> 5) + rep * 16;
        const int c = t & 31;
        const int phys = c ^ ((il >> 1) & 15);
        short8 v = *(const short8*)(lds + il * 256 + phys * 8);
        *(short8*)(Ep + (size_t)(i0 + il) * LB_ + j0 + c * 8) = v;
    }
}

// ---------------------------------------------------------------------------
// GEMM2+3 merged: zc<16 -> feature_a (E . bT^T), zc>=16 -> feature_b (ET.aT^T)
// Grid: 256 blocks, g = qq*32 + zc -> XCD zc%8 (A-tile/B-panel L2 sharing).
// Keeps counted schedule (SCHED=0): the R2 winner for this kernel.
// ---------------------------------------------------------------------------
__global__ __launch_bounds__(512, 2) void k_gemm_feat(
    const unsigned short* __restrict__ E, const unsigned short* __restrict__ ET,
    const unsigned short* __restrict__ aT, const unsigned short* __restrict__ bT,
    const int* __restrict__ mask_a, const int* __restrict__ mask_b,
    const int* __restrict__ nA, const int* __restrict__ nB,
    const float* __restrict__ l_row, const float* __restrict__ l_col,
    const float* __restrict__ mean_a, const float* __restrict__ mean_b,
    float* __restrict__ out)
{
    __shared__ unsigned short lds[65536];

    const int g = blockIdx.x;
    const int zc = g & 31;
    const int qq = g >> 5;                       // 0..7
    const int n0 = (qq & 1) * 256, m0 = (qq >> 1) * 256;

    const int batch = zc & 15;
    const bool isA = zc < 16;
    const unsigned short* Amat = (isA ? E : ET) + (size_t)batch * 1024 * 1024;
    const unsigned short* Bm   = (isA ? bT : aT) + (size_t)batch * H_ * 1024;
    const int* mp   = (isA ? mask_a : mask_b) + batch * 1024;
    const int nn    = (isA ? nB : nA)[batch];
    const float* sp = (isA ? l_row : l_col) + batch * 1024;
    const float* mv = (isA ? mean_b : mean_a) + batch * H_;
    float* op = out + (isA ? (size_t)0 : (size_t)NB_ * LA_ * H_) + (size_t)batch * 1024 * H_;

    f32x4 acc[8][4];
#pragma unroll
    for (int x = 0; x < 8; x++)
#pragma unroll
        for (int y = 0; y < 4; y++) acc[x][y] = 0;

    gemm_core256<0>(Amat + (size_t)m0 * 1024, Bm + (size_t)n0 * 1024,
                    1024, 1024, 1024, lds, acc);

    const int t = threadIdx.x, w = t >> 6, lane = t & 63;
    const int wr = w >> 2, wc = w & 3, lm = lane & 15, q = lane >> 4;

    float mval[4];
#pragma unroll
    for (int fn = 0; fn < 4; fn++) mval[fn] = mv[n0 + wc * 64 + fn * 16 + lm];

#pragma unroll
    for (int fm = 0; fm < 8; fm++) {
        const int ib = m0 + wr * 128 + fm * 16 + q * 4;
#pragma unroll
        for (int r = 0; r < 4; r++) {
            const int i = ib + r;
            const bool valid = (mp[i] != 0) && (nn > 0);
            const float inv = valid ? 1.0f / sp[i] : 0.0f;
#pragma unroll
            for (int fn = 0; fn < 4; fn++) {
                const int d = n0 + wc * 64 + fn * 16 + lm;
                op[(size_t)i * H_ + d] = valid ? acc[fm][fn][r] * inv : mval[fn];
            }
        }
    }
}

// ---------------------------------------------------------------------------
// prep: block-owned column panels -> NO atomics (the old LDS-atomic mean
// path made prep ~100 us, 5x its 128 MB roofline).
// Blocks 0..255: (sel, batch, 64-d strip); loop over all 1024 tokens:
//   fp32 -> bf16 row-major + LDS-transposed bf16, column sums in registers,
//   shfl + small-LDS reduce -> direct mean store (single writer).
// Blocks 256..287: zero l_row/l_col (128 KB) + per-batch mask counts
// (replaces k_init -> one fewer dispatch).
// ---------------------------------------------------------------------------
__global__ __launch_bounds__(256) void k_prep(
    const float* __restrict__ a, const float* __restrict__ b,
    unsigned short* __restrict__ aN, unsigned short* __restrict__ bN,
    unsigned short* __restrict__ aT, unsigned short* __restrict__ bT,
    float* __restrict__ mean_a, float* __restrict__ mean_b,
    const int* __restrict__ mask_a, const int* __restrict__ mask_b,
    int* __restrict__ nA, int* __restrict__ nB,
    float* __restrict__ zero_base)
{
    const int g = blockIdx.x, t = threadIdx.x;
    if (g >= 256) {
        const int s = g - 256;                   // 0..31
        *(float4*)(zero_base + ((size_t)s * 256 + t) * 4) = make_float4(0, 0, 0, 0);
        const int batch = s & 15, which = s >> 4;
        const int* m = (which ? mask_b : mask_a) + batch * 1024;
        int cnt = m[t] + m[t + 256] + m[t + 512] + m[t + 768];
        __shared__ int red[256];
        red[t] = cnt;
        __syncthreads();
        for (int off = 128; off; off >>= 1) {
            if (t < off) red[t] += red[t + off];
            __syncthreads();
        }
        if (t == 0) (which ? nB : nA)[batch] = red[0];
        return;
    }
    const int dstrip = g & 7, batch = (g >> 3) & 15, sel = g >> 7;
    const float* src = (sel ? b : a) + (size_t)batch * 1024 * H_;
    unsigned short* np = (sel ? bN : aN) + (size_t)batch * 1024 * H_;
    unsigned short* tp = (sel ? bT : aT) + (size_t)batch * H_ * 1024;
    float* mdst = (sel ? mean_b : mean_a) + batch * H_;
    const int d0 = dstrip * 64;

    __shared__ unsigned short lds[64][68];
    __shared__ float cs[4][64];
    const int c4 = (t & 15) * 4;
    float colsum[4] = {0.f, 0.f, 0.f, 0.f};
    for (int i0 = 0; i0 < 1024; i0 += 64) {
#pragma unroll
        for (int it = 0; it < 4; it++) {
            const int r = (t >> 4) + it * 16;
            float4 v = *(const float4*)(src + (size_t)(i0 + r) * H_ + d0 + c4);
            colsum[0] += v.x; colsum[1] += v.y; colsum[2] += v.z; colsum[3] += v.w;
            ushort4 u = make_ushort4(f2bf(v.x), f2bf(v.y), f2bf(v.z), f2bf(v.w));
            *(ushort4*)(np + (size_t)(i0 + r) * H_ + d0 + c4) = u;
            *(ushort4*)&lds[r][c4] = u;
        }
        __syncthreads();
#pragma unroll
        for (int it = 0; it < 4; it++) {
            const int dd = (t >> 4) + it * 16;
            const int i4 = (t & 15) * 4;
            ushort4 u = make_ushort4(lds[i4][dd], lds[i4 + 1][dd],
                                     lds[i4 + 2][dd], lds[i4 + 3][dd]);
            *(ushort4*)(tp + (size_t)(d0 + dd) * 1024 + i0 + i4) = u;
        }
        __syncthreads();
    }
    // columns are shared by threads t, t^16, t^32 (within wave) x 4 waves
#pragma unroll
    for (int j = 0; j < 4; j++) {
        colsum[j] += __shfl_xor(colsum[j], 16, 64);
        colsum[j] += __shfl_xor(colsum[j], 32, 64);
    }
    const int w = t >> 6, lane = t & 63;
    if (lane < 16) {
#pragma unroll
        for (int j = 0; j < 4; j++) cs[w][c4 + j] = colsum[j];
    }
    __syncthreads();
    if (t < 64) mdst[d0 + t] = (cs[0][t] + cs[1][t] + cs[2][t] + cs[3][t]) * (1.0f / 1024.0f);
}

// ---------------------------------------------------------------------------
extern "C" void kernel_launch(void* const* d_in, const int* in_sizes, int n_in,
                              void* d_out, int out_size, void* d_ws, size_t ws_size,
                              hipStream_t stream)
{
    const float* a      = (const float*)d_in[0];
    const float* b      = (const float*)d_in[1];
    const int*   mask_a = (const int*)d_in[2];
    const int*   mask_b = (const int*)d_in[3];
    const float* temp   = (const float*)d_in[4];
    float* out = (float*)d_out;

    // workspace layout (~128.2 MiB)
    char* ws = (char*)d_ws;
    size_t off = 0;
    unsigned short* E    = (unsigned short*)(ws + off); off += (size_t)NB_ * LA_ * LB_ * 2;  // 32 MiB
    unsigned short* ET   = (unsigned short*)(ws + off); off += (size_t)NB_ * LB_ * LA_ * 2;  // 32 MiB
    unsigned short* a_bf = (unsigned short*)(ws + off); off += (size_t)NB_ * LA_ * H_ * 2;   // 16 MiB
    unsigned short* b_bf = (unsigned short*)(ws + off); off += (size_t)NB_ * LB_ * H_ * 2;   // 16 MiB
    unsigned short* aT   = (unsigned short*)(ws + off); off += (size_t)NB_ * H_ * LA_ * 2;   // 16 MiB
    unsigned short* bT   = (unsigned short*)(ws + off); off += (size_t)NB_ * H_ * LB_ * 2;   // 16 MiB
    float* l_row  = (float*)(ws + off); off += (size_t)NB_ * LA_ * 4;   // zeroed region start
    float* l_col  = (float*)(ws + off); off += (size_t)NB_ * LB_ * 4;
    float* mean_a = (float*)(ws + off); off += (size_t)NB_ * H_ * 4;
    float* mean_b = (float*)(ws + off); off += (size_t)NB_ * H_ * 4;
    int*   nA     = (int*)(ws + off); off += 64;
    int*   nB     = (int*)(ws + off); off += 64;

    // prep (also zeroes l_row/l_col and computes mask counts; k_init gone)
    k_prep<<<dim3(288), 256, 0, stream>>>(
        a, b, a_bf, b_bf, aT, bT, mean_a, mean_b,
        mask_a, mask_b, nA, nB, l_row);

    k_gemm_attn<<<dim3(256), 512, 0, stream>>>(
        a_bf, b_bf, mask_a, mask_b, temp, E, ET, l_row, l_col);

    k_gemm_feat<<<dim3(256), 512, 0, stream>>>(
        E, ET, aT, bT, mask_a, mask_b, nA, nB, l_row, l_col, mean_a, mean_b, out);
}